// Round 2
// baseline (1577.786 us; speedup 1.0000x reference)
//
#include <hip/hip_runtime.h>
#include <cstdint>
#include <cstddef>

typedef __bf16 bf16_t;
typedef __bf16 bf16x8 __attribute__((ext_vector_type(8)));
typedef __bf16 bf16x4 __attribute__((ext_vector_type(4)));
typedef float floatx4 __attribute__((ext_vector_type(4)));

// ---------------------------------------------------------------- helpers
__device__ __forceinline__ void async16(const bf16_t* g, bf16_t* l) {
  __builtin_amdgcn_global_load_lds(
      (const __attribute__((address_space(1))) unsigned int*)g,
      (__attribute__((address_space(3))) unsigned int*)l, 16, 0, 0);
}

template<int N>
__device__ __forceinline__ float rowror(float x) {
  return __int_as_float(__builtin_amdgcn_update_dpp(
      0, __float_as_int(x), 0x120 | N, 0xf, 0xf, false));
}
// sum across 16-lane DPP row (all lanes get total)
__device__ __forceinline__ float rowsum16(float x) {
  x += rowror<8>(x);
  x += rowror<4>(x);
  x += rowror<2>(x);
  x += rowror<1>(x);
  return x;
}

__device__ __forceinline__ float siluf(float x) { return x / (1.f + __expf(-x)); }

#define MFMA16(a, b, c) __builtin_amdgcn_mfma_f32_16x16x32_bf16(a, b, c, 0, 0, 0)

// ---------------------------------------------------------------- fp32 -> bf16
__global__ __launch_bounds__(256) void k_cvt(const float* __restrict__ in,
                                             bf16_t* __restrict__ out, int n4) {
  int i = blockIdx.x * 256 + threadIdx.x;
  if (i >= n4) return;
  const float4 f = ((const float4*)in)[i];
  bf16x4 r;
  r[0] = (bf16_t)f.x; r[1] = (bf16_t)f.y; r[2] = (bf16_t)f.z; r[3] = (bf16_t)f.w;
  ((bf16x4*)out)[i] = r;
}

// W_b rows 0..31, W_a rows 32..63, zeros 64..127
__global__ __launch_bounds__(256) void k_build_wba(const float* __restrict__ wb,
                                                   const float* __restrict__ wa,
                                                   bf16_t* __restrict__ out) {
  int i = blockIdx.x * 256 + threadIdx.x;
  int e = i * 4;
  int row = e >> 11;
  int col = e & 2047;
  float4 f = make_float4(0.f, 0.f, 0.f, 0.f);
  if (row < 32)      f = *(const float4*)&wb[row * 2048 + col];
  else if (row < 64) f = *(const float4*)&wa[(row - 32) * 2048 + col];
  bf16x4 r;
  r[0] = (bf16_t)f.x; r[1] = (bf16_t)f.y; r[2] = (bf16_t)f.z; r[3] = (bf16_t)f.w;
  *(bf16x4*)&out[e] = r;
}

// ---------------------------------------------------------------- GEMM (m97-style)
template<bool OUT_BF16>
__global__ __launch_bounds__(256) void gemm_bt(const bf16_t* __restrict__ A,
                                               const bf16_t* __restrict__ B,
                                               void* __restrict__ Cout,
                                               int M, int N, int K) {
  __shared__ __align__(16) bf16_t As[4096];
  __shared__ __align__(16) bf16_t Bs[4096];
  const int tid  = threadIdx.x;
  const int lane = tid & 63;
  const int wave = tid >> 6;
  const int quad = lane >> 4;
  const int l16  = lane & 15;
  const int wr   = (wave >> 1) * 64;
  const int wc   = (wave & 1) * 64;
  const int m0   = blockIdx.y * 128;
  const int n0   = blockIdx.x * 128;
  const int ra   = tid >> 2;
  const int ca   = (tid & 3) * 8;

  const bf16_t* gA = A + (size_t)(m0 + ra) * K + ca;
  const bf16_t* gB = B + (size_t)(n0 + ra) * K + ca;
  bf16_t* lA = &As[tid * 8];
  bf16_t* lB = &Bs[tid * 8];

  floatx4 acc[4][4] = {};

  for (int k0 = 0; k0 < K; k0 += 32) {
    __syncthreads();
    async16(gA + k0, lA);
    async16(gA + k0 + (size_t)64 * K, lA + 2048);
    async16(gB + k0, lB);
    async16(gB + k0 + (size_t)64 * K, lB + 2048);
    __syncthreads();
    bf16x8 af[4], bfr[4];
#pragma unroll
    for (int i = 0; i < 4; ++i) {
      af[i]  = *(const bf16x8*)&As[(wr + i * 16 + l16) * 32 + quad * 8];
      bfr[i] = *(const bf16x8*)&Bs[(wc + i * 16 + l16) * 32 + quad * 8];
    }
#pragma unroll
    for (int mi = 0; mi < 4; ++mi)
#pragma unroll
      for (int ni = 0; ni < 4; ++ni)
        acc[mi][ni] = MFMA16(af[mi], bfr[ni], acc[mi][ni]);
  }

#pragma unroll
  for (int mi = 0; mi < 4; ++mi) {
#pragma unroll
    for (int ni = 0; ni < 4; ++ni) {
      const int row = m0 + wr + mi * 16 + quad * 4;
      const int col = n0 + wc + ni * 16 + l16;
#pragma unroll
      for (int r = 0; r < 4; ++r) {
        if (OUT_BF16)
          ((bf16_t*)Cout)[(size_t)(row + r) * N + col] = (bf16_t)acc[mi][ni][r];
        else
          ((float*)Cout)[(size_t)(row + r) * N + col] = acc[mi][ni][r];
      }
    }
  }
}

// ---------------------------------------------------------------- beta / g (transposed [h][t] layout)
__global__ __launch_bounds__(256) void k_betag(const float* __restrict__ cba,
                                               const float* __restrict__ A_log,
                                               const float* __restrict__ dtb,
                                               float* __restrict__ beta_t,
                                               float* __restrict__ g_t) {
  int i = blockIdx.x * 256 + threadIdx.x;  // T*32
  int t = i >> 5, h = i & 31;
  float b = cba[t * 128 + h];
  float a = cba[t * 128 + 32 + h];
  beta_t[h * 4096 + t] = 1.f / (1.f + __expf(-b));
  float x = a + dtb[h];
  float sp = (x > 20.f) ? x : log1pf(__expf(x));
  g_t[h * 4096 + t] = -__expf(A_log[h]) * sp;
}

// ---------------------------------------------------------------- conv4 + silu + l2norm
__global__ __launch_bounds__(128) void k_conv(const bf16_t* __restrict__ mixed,
                                              const float* __restrict__ cw,
                                              bf16_t* __restrict__ qo,
                                              bf16_t* __restrict__ ko,
                                              bf16_t* __restrict__ vo) {
  const int t = blockIdx.y;
  const int grp = blockIdx.x;
  const int d = threadIdx.x;
  const int c = grp * 128 + d;
  const float4 wv = *(const float4*)&cw[c * 4];
  float acc = 0.f;
#pragma unroll
  for (int i = 0; i < 4; ++i) {
    int tt = t - 3 + i;
    if (tt >= 0) acc += ((const float*)&wv)[i] * (float)mixed[(size_t)tt * 8192 + c];
  }
  float val = siluf(acc);
  if (grp < 32) {
    __shared__ float red[2];
    float s = val * val;
#pragma unroll
    for (int m = 1; m < 64; m <<= 1) s += __shfl_xor(s, m);
    if ((threadIdx.x & 63) == 0) red[threadIdx.x >> 6] = s;
    __syncthreads();
    float r = rsqrtf(red[0] + red[1] + 1e-6f);
    if (grp < 16)
      qo[((size_t)t * 16 + grp) * 128 + d] = (bf16_t)(val * r * 0.08838834764831845f); // DK^-0.5 folded
    else
      ko[((size_t)t * 16 + grp - 16) * 128 + d] = (bf16_t)(val * r);
  } else {
    vo[((size_t)t * 32 + grp - 32) * 128 + d] = (bf16_t)val;
  }
}

// ---------------------------------------------------------------- chunk scores: KK^T, QK^T, K^T
// grid = 64 chunks x 16 kheads. Raw (undecayed) scores, bf16 out.
__global__ __launch_bounds__(256) void k_scores(const bf16_t* __restrict__ qg,
                                                const bf16_t* __restrict__ kg,
                                                bf16_t* __restrict__ sK,
                                                bf16_t* __restrict__ sQ,
                                                bf16_t* __restrict__ kt) {
  const int cc = blockIdx.x >> 4;
  const int kh = blockIdx.x & 15;
  const int t0 = cc * 64;
  const int tid = threadIdx.x, lane = tid & 63, wave = tid >> 6;
  const int quad = lane >> 4, l16 = lane & 15;
  __shared__ __align__(16) bf16_t lsK[64 * 136];
  __shared__ __align__(16) bf16_t lsQ[64 * 136];
  {
    const int t = tid >> 2, p0 = (tid & 3) * 32;
    const bf16_t* kr = kg + ((size_t)(t0 + t) * 16 + kh) * 128 + p0;
    const bf16_t* qr = qg + ((size_t)(t0 + t) * 16 + kh) * 128 + p0;
#pragma unroll
    for (int j = 0; j < 4; ++j) {
      *(bf16x8*)&lsK[t * 136 + p0 + j * 8] = *(const bf16x8*)&kr[j * 8];
      *(bf16x8*)&lsQ[t * 136 + p0 + j * 8] = *(const bf16x8*)&qr[j * 8];
    }
  }
  __syncthreads();
  const int mr = (wave >> 1) * 32, nr = (wave & 1) * 32;
  floatx4 ak[2][2] = {}, aq[2][2] = {};
#pragma unroll
  for (int ks = 0; ks < 4; ++ks) {
    bf16x8 yf[2], xk[2], xq[2];
#pragma unroll
    for (int i = 0; i < 2; ++i) {
      yf[i] = *(const bf16x8*)&lsK[(nr + i * 16 + l16) * 136 + ks * 32 + quad * 8];
      xk[i] = *(const bf16x8*)&lsK[(mr + i * 16 + l16) * 136 + ks * 32 + quad * 8];
      xq[i] = *(const bf16x8*)&lsQ[(mr + i * 16 + l16) * 136 + ks * 32 + quad * 8];
    }
#pragma unroll
    for (int i = 0; i < 2; ++i)
#pragma unroll
      for (int j = 0; j < 2; ++j) {
        ak[i][j] = MFMA16(xk[i], yf[j], ak[i][j]);
        aq[i][j] = MFMA16(xq[i], yf[j], aq[i][j]);
      }
  }
  bf16_t* skb = sK + (size_t)(cc * 16 + kh) * 4096;
  bf16_t* sqb = sQ + (size_t)(cc * 16 + kh) * 4096;
#pragma unroll
  for (int i = 0; i < 2; ++i)
#pragma unroll
    for (int j = 0; j < 2; ++j)
#pragma unroll
      for (int r = 0; r < 4; ++r) {
        int row = mr + i * 16 + quad * 4 + r;
        int col = nr + j * 16 + l16;
        skb[row * 64 + col] = (bf16_t)ak[i][j][r];
        sqb[row * 64 + col] = (bf16_t)aq[i][j][r];
      }
  // K^T (128 x 64) for the state-update B-operand
  {
    const int dk = tid >> 1, sh = (tid & 1) * 32;
    bf16_t* ktb = kt + (size_t)(cc * 16 + kh) * 8192 + (size_t)dk * 64 + sh;
#pragma unroll
    for (int j = 0; j < 4; ++j) {
      bf16x8 v;
#pragma unroll
      for (int e = 0; e < 8; ++e) v[e] = lsK[(sh + j * 8 + e) * 136 + dk];
      *(bf16x8*)&ktb[j * 8] = v;
    }
  }
}

// ---------------------------------------------------------------- chunked WY delta-rule chain
// grid = 32 heads x 8 dv-slices(16). 256 thr. Sequential over 64 chunks of L=64.
__global__ __launch_bounds__(256) void k_chain(const bf16_t* __restrict__ qg,
                                               const bf16_t* __restrict__ kg,
                                               const bf16_t* __restrict__ vg,
                                               const bf16_t* __restrict__ sK,
                                               const bf16_t* __restrict__ sQ,
                                               const bf16_t* __restrict__ kt,
                                               const float* __restrict__ bb_t,
                                               const float* __restrict__ gb_t,
                                               float* __restrict__ o) {
  const int h = blockIdx.x >> 3;
  const int sl = blockIdx.x & 7;
  const int dv0 = sl * 16;
  const int kh = h >> 1;
  const int tid = threadIdx.x;
  const int lane = tid & 63;
  const int wave = tid >> 6;
  const int quad = lane >> 4;
  const int l16 = lane & 15;

  __shared__ float lsG[64], lsA[64], lsSc[64], lsBeta[64];
  __shared__ __align__(16) bf16_t lsC[64 * 72];   // -beta*R*KK, permuted cols
  __shared__ __align__(16) bf16_t lsM[64 * 72];   // R*QK, causal-inclusive
  __shared__ float lsVt[64 * 16];                 // B (rhs)
  __shared__ __align__(16) bf16_t lsVs[16 * 72];  // V~^T
  __shared__ __align__(16) bf16_t lsVsc[16 * 72]; // V~^T * exp(G_L - G_s)
  __shared__ __align__(16) bf16_t lsS[16 * 136];  // state^T bf16 [dv][dk]

  floatx4 stacc[2] = {};  // fp32 state master, C-layout M=16(dv) N=128(dk), wave n-tiles {2w,2w+1}
  for (int i = tid; i < 16 * 136; i += 256) lsS[i] = (bf16_t)0.f;

  const float* gbase = gb_t + (size_t)h * 4096;
  const float* bbase = bb_t + (size_t)h * 4096;

  for (int cc = 0; cc < 64; ++cc) {
    const int t0 = cc * 64;
    // phase 1: within-chunk decay prefix (wave 0)
    if (wave == 0) {
      float gv = gbase[t0 + lane];
#pragma unroll
      for (int off = 1; off < 64; off <<= 1) {
        float n = __shfl_up(gv, off);
        if (lane >= off) gv += n;
      }
      float GL = __shfl(gv, 63);
      lsG[lane] = gv;
      lsA[lane] = __expf(gv);
      lsSc[lane] = __expf(GL - gv);
      lsBeta[lane] = bbase[t0 + lane];
    }
    __syncthreads();  // also protects lsS rewrite (phase 6) vs phase-2a reads

    // phase 2a: kv0 = K@S0^T, qs0 = Q@S0^T (wave -> rows wave*16..+15)
    floatx4 kv0 = {0.f, 0.f, 0.f, 0.f}, qs0 = {0.f, 0.f, 0.f, 0.f};
    {
      const bf16_t* krow = kg + ((size_t)(t0 + wave * 16 + l16) * 16 + kh) * 128;
      const bf16_t* qrow = qg + ((size_t)(t0 + wave * 16 + l16) * 16 + kh) * 128;
#pragma unroll
      for (int ks = 0; ks < 4; ++ks) {
        bf16x8 yf = *(const bf16x8*)&lsS[l16 * 136 + ks * 32 + quad * 8];
        bf16x8 xk = *(const bf16x8*)&krow[ks * 32 + quad * 8];
        bf16x8 xq = *(const bf16x8*)&qrow[ks * 32 + quad * 8];
        kv0 = MFMA16(xk, yf, kv0);
        qs0 = MFMA16(xq, yf, qs0);
      }
    }
    // phase 2b: build C (negated, permuted) and M
    {
      const int t = tid >> 2, s0 = (tid & 3) * 16;
      const float Gt = lsG[t], bt = lsBeta[t];
      const bf16_t* skr = sK + (size_t)(cc * 16 + kh) * 4096 + t * 64 + s0;
      const bf16_t* sqr = sQ + (size_t)(cc * 16 + kh) * 4096 + t * 64 + s0;
#pragma unroll
      for (int j = 0; j < 16; ++j) {
        int s = s0 + j;
        float r = __expf(Gt - lsG[s]);
        float cn = (s < t) ? (-bt * r * (float)skr[j]) : 0.f;
        float mm = (s <= t) ? (r * (float)sqr[j]) : 0.f;
        lsC[t * 72 + j * 4 + (s0 >> 4)] = (bf16_t)cn;  // [t][(s&15)*4 + (s>>4)]
        lsM[t * 72 + s] = (bf16_t)mm;
      }
    }
    // phase 2c: B = beta*(v - A_t*kv0) -> lsVt
#pragma unroll
    for (int r = 0; r < 4; ++r) {
      int t = wave * 16 + quad * 4 + r;
      float vv = (float)vg[((size_t)(t0 + t) * 32 + h) * 128 + dv0 + l16];
      lsVt[t * 16 + l16] = lsBeta[t] * (vv - lsA[t] * kv0[r]);
    }
    __syncthreads();

    // phase 3: forward substitution (I+C)V~ = B. lanes: s_lane = l16, col c = wave*4+quad
    float vfull[4] = {0.f, 0.f, 0.f, 0.f};
    {
      const int c = wave * 4 + quad;
      bf16x4 cnb[4];
      float bb4[4], sc4[4];
#pragma unroll
      for (int t = 0; t < 4; ++t) {
        cnb[t] = *(const bf16x4*)&lsC[t * 72 + l16 * 4];
        bb4[t] = lsVt[t * 16 + c];
        sc4[t] = lsSc[t];
      }
#pragma unroll
      for (int t = 0; t < 64; ++t) {
        bf16x4 cn4 = cnb[t & 3];
        float bv = bb4[t & 3];
        float scv = sc4[t & 3];
        float p = (float)cn4[0] * vfull[0] + (float)cn4[1] * vfull[1] +
                  (float)cn4[2] * vfull[2] + (float)cn4[3] * vfull[3];
        float val = bv + rowsum16(p);
        if (t < 60) {
          cnb[t & 3] = *(const bf16x4*)&lsC[(t + 4) * 72 + l16 * 4];
          bb4[t & 3] = lsVt[(t + 4) * 16 + c];
          sc4[t & 3] = lsSc[t + 4];
        }
        vfull[t >> 4] = (l16 == (t & 15)) ? val : vfull[t >> 4];
        if (l16 == (t & 15)) {
          lsVs[c * 72 + t] = (bf16_t)val;
          lsVsc[c * 72 + t] = (bf16_t)(val * scv);
        }
      }
    }
    __syncthreads();

    // phase 4: o = A_t*qs0 + M @ V~ ; store
    {
      floatx4 oacc;
#pragma unroll
      for (int r = 0; r < 4; ++r) oacc[r] = lsA[wave * 16 + quad * 4 + r] * qs0[r];
#pragma unroll
      for (int ks = 0; ks < 2; ++ks) {
        bf16x8 xf = *(const bf16x8*)&lsM[(wave * 16 + l16) * 72 + ks * 32 + quad * 8];
        bf16x8 yf = *(const bf16x8*)&lsVs[l16 * 72 + ks * 32 + quad * 8];
        oacc = MFMA16(xf, yf, oacc);
      }
#pragma unroll
      for (int r = 0; r < 4; ++r) {
        int t = wave * 16 + quad * 4 + r;
        o[((size_t)(t0 + t) * 32 + h) * 128 + dv0 + l16] = oacc[r];
      }
    }
    // phase 5: state update S' = A_L*S + (V~sc)^T-style MFMA with K^T
    {
      float AL = lsA[63];
#pragma unroll
      for (int nt = 0; nt < 2; ++nt)
#pragma unroll
        for (int r = 0; r < 4; ++r) stacc[nt][r] *= AL;
      const bf16_t* ktb = kt + (size_t)(cc * 16 + kh) * 8192;
#pragma unroll
      for (int ks = 0; ks < 2; ++ks) {
        bf16x8 xf = *(const bf16x8*)&lsVsc[l16 * 72 + ks * 32 + quad * 8];
#pragma unroll
        for (int nt = 0; nt < 2; ++nt) {
          bf16x8 yf = *(const bf16x8*)&ktb[(size_t)((wave * 2 + nt) * 16 + l16) * 64 + ks * 32 + quad * 8];
          stacc[nt] = MFMA16(xf, yf, stacc[nt]);
        }
      }
    }
    __syncthreads();
    // phase 6: refresh bf16 state copy
#pragma unroll
    for (int nt = 0; nt < 2; ++nt)
#pragma unroll
      for (int r = 0; r < 4; ++r)
        lsS[(quad * 4 + r) * 136 + (wave * 2 + nt) * 16 + l16] = (bf16_t)stacc[nt][r];
  }
}

// ---------------------------------------------------------------- RMSNorm * silu(z)
__global__ __launch_bounds__(64) void k_gate(const float* __restrict__ o,
                                             const bf16_t* __restrict__ z,
                                             const float* __restrict__ nw,
                                             bf16_t* __restrict__ y) {
  const int h = blockIdx.x, t = blockIdx.y, l = threadIdx.x;
  const float* orow = o + ((size_t)t * 32 + h) * 128;
  float o0 = orow[l], o1 = orow[l + 64];
  float s = o0 * o0 + o1 * o1;
#pragma unroll
  for (int m = 1; m < 64; m <<= 1) s += __shfl_xor(s, m);
  float r = rsqrtf(s * (1.f / 128.f) + 1e-6f);
  const bf16_t* zrow = z + (size_t)t * 4096 + h * 128;
  float z0 = (float)zrow[l], z1 = (float)zrow[l + 64];
  bf16_t* yrow = y + (size_t)t * 4096 + h * 128;
  yrow[l]      = (bf16_t)(o0 * r * nw[l] * siluf(z0));
  yrow[l + 64] = (bf16_t)(o1 * r * nw[l + 64] * siluf(z1));
}

// ---------------------------------------------------------------- launch
extern "C" void kernel_launch(void* const* d_in, const int* in_sizes, int n_in,
                              void* d_out, int out_size, void* d_ws, size_t ws_size,
                              hipStream_t stream) {
  const float* hidden = (const float*)d_in[0];
  const float* W_qkv  = (const float*)d_in[1];
  const float* W_z    = (const float*)d_in[2];
  const float* W_b    = (const float*)d_in[3];
  const float* W_a    = (const float*)d_in[4];
  const float* conv_w = (const float*)d_in[5];
  const float* dt_b   = (const float*)d_in[6];
  const float* A_log  = (const float*)d_in[7];
  const float* norm_w = (const float*)d_in[8];
  const float* W_out  = (const float*)d_in[9];
  float* out = (float*)d_out;

  char* w = (char*)d_ws;
  const size_t MB = 1024 * 1024;
  bf16_t* hs    = (bf16_t*)(w + 0 * MB);    // 16 MiB
  bf16_t* wqkv  = (bf16_t*)(w + 16 * MB);   // 32 MiB; region reused: scores+KT, then y
  bf16_t* ybuf  = wqkv;
  bf16_t* sKb   = (bf16_t*)(w + 16 * MB);   // 8 MiB  (after qkv GEMM done)
  bf16_t* sQb   = (bf16_t*)(w + 24 * MB);   // 8 MiB
  bf16_t* ktb   = (bf16_t*)(w + 32 * MB);   // 16 MiB
  bf16_t* wz    = (bf16_t*)(w + 48 * MB);   // 16 MiB
  bf16_t* wout  = (bf16_t*)(w + 64 * MB);   // 16 MiB
  bf16_t* wba   = (bf16_t*)(w + 80 * MB);   // 0.5 MiB
  bf16_t* mixed = (bf16_t*)(w + 81 * MB);   // 64 MiB (reused as o fp32)
  float*  obuf  = (float*)mixed;
  bf16_t* zbuf  = (bf16_t*)(w + 145 * MB);  // 32 MiB
  float*  cba   = (float*)(w + 177 * MB);   // 2 MiB
  bf16_t* qb    = (bf16_t*)(w + 179 * MB);  // 16 MiB
  bf16_t* kb    = (bf16_t*)(w + 195 * MB);  // 16 MiB
  bf16_t* vb    = (bf16_t*)(w + 211 * MB);  // 32 MiB
  float*  betab = (float*)(w + 243 * MB);   // 0.5 MiB ([h][t])
  float*  gbuf  = (float*)(w + 244 * MB);   // 0.5 MiB ([h][t])

  k_cvt<<<8192, 256, 0, stream>>>(hidden, hs, 2097152);
  k_cvt<<<16384, 256, 0, stream>>>(W_qkv, wqkv, 4194304);
  k_cvt<<<8192, 256, 0, stream>>>(W_z, wz, 2097152);
  k_cvt<<<8192, 256, 0, stream>>>(W_out, wout, 2097152);
  k_build_wba<<<256, 256, 0, stream>>>(W_b, W_a, wba);

  gemm_bt<true><<<dim3(64, 32), 256, 0, stream>>>(hs, wqkv, mixed, 4096, 8192, 2048);
  gemm_bt<true><<<dim3(32, 32), 256, 0, stream>>>(hs, wz, zbuf, 4096, 4096, 2048);
  gemm_bt<false><<<dim3(1, 32), 256, 0, stream>>>(hs, wba, cba, 4096, 128, 2048);
  k_betag<<<512, 256, 0, stream>>>(cba, A_log, dt_b, betab, gbuf);

  k_conv<<<dim3(64, 4096), 128, 0, stream>>>(mixed, conv_w, qb, kb, vb);

  // chunked WY delta rule (scores region overlays wqkv -- qkv GEMM already done;
  // ybuf overlays scores -- written only after k_chain consumed them)
  k_scores<<<1024, 256, 0, stream>>>(qb, kb, sKb, sQb, ktb);
  k_chain<<<256, 256, 0, stream>>>(qb, kb, vb, sKb, sQb, ktb, betab, gbuf, obuf);

  k_gate<<<dim3(32, 4096), 64, 0, stream>>>(obuf, zbuf, norm_w, ybuf);
  gemm_bt<false><<<dim3(16, 32), 256, 0, stream>>>(ybuf, wout, out, 4096, 2048, 4096);
}

// Round 3
// 1074.500 us; speedup vs baseline: 1.4684x; 1.4684x over previous
//
#include <hip/hip_runtime.h>
#include <cstdint>
#include <cstddef>

typedef __bf16 bf16_t;
typedef __bf16 bf16x8 __attribute__((ext_vector_type(8)));
typedef __bf16 bf16x4 __attribute__((ext_vector_type(4)));
typedef float floatx4 __attribute__((ext_vector_type(4)));

// ---------------------------------------------------------------- helpers
__device__ __forceinline__ void async16(const bf16_t* g, bf16_t* l) {
  __builtin_amdgcn_global_load_lds(
      (const __attribute__((address_space(1))) unsigned int*)g,
      (__attribute__((address_space(3))) unsigned int*)l, 16, 0, 0);
}

__device__ __forceinline__ float siluf(float x) { return x / (1.f + __expf(-x)); }

#define MFMA16(a, b, c) __builtin_amdgcn_mfma_f32_16x16x32_bf16(a, b, c, 0, 0, 0)

// ---------------------------------------------------------------- fp32 -> bf16
__global__ __launch_bounds__(256) void k_cvt(const float* __restrict__ in,
                                             bf16_t* __restrict__ out, int n4) {
  int i = blockIdx.x * 256 + threadIdx.x;
  if (i >= n4) return;
  const float4 f = ((const float4*)in)[i];
  bf16x4 r;
  r[0] = (bf16_t)f.x; r[1] = (bf16_t)f.y; r[2] = (bf16_t)f.z; r[3] = (bf16_t)f.w;
  ((bf16x4*)out)[i] = r;
}

// W_b rows 0..31, W_a rows 32..63, zeros 64..127
__global__ __launch_bounds__(256) void k_build_wba(const float* __restrict__ wb,
                                                   const float* __restrict__ wa,
                                                   bf16_t* __restrict__ out) {
  int i = blockIdx.x * 256 + threadIdx.x;
  int e = i * 4;
  int row = e >> 11;
  int col = e & 2047;
  float4 f = make_float4(0.f, 0.f, 0.f, 0.f);
  if (row < 32)      f = *(const float4*)&wb[row * 2048 + col];
  else if (row < 64) f = *(const float4*)&wa[(row - 32) * 2048 + col];
  bf16x4 r;
  r[0] = (bf16_t)f.x; r[1] = (bf16_t)f.y; r[2] = (bf16_t)f.z; r[3] = (bf16_t)f.w;
  *(bf16x4*)&out[e] = r;
}

// ---------------------------------------------------------------- GEMM (m97-style)
template<bool OUT_BF16>
__global__ __launch_bounds__(256) void gemm_bt(const bf16_t* __restrict__ A,
                                               const bf16_t* __restrict__ B,
                                               void* __restrict__ Cout,
                                               int M, int N, int K) {
  __shared__ __align__(16) bf16_t As[4096];
  __shared__ __align__(16) bf16_t Bs[4096];
  const int tid  = threadIdx.x;
  const int lane = tid & 63;
  const int wave = tid >> 6;
  const int quad = lane >> 4;
  const int l16  = lane & 15;
  const int wr   = (wave >> 1) * 64;
  const int wc   = (wave & 1) * 64;
  const int m0   = blockIdx.y * 128;
  const int n0   = blockIdx.x * 128;
  const int ra   = tid >> 2;
  const int ca   = (tid & 3) * 8;

  const bf16_t* gA = A + (size_t)(m0 + ra) * K + ca;
  const bf16_t* gB = B + (size_t)(n0 + ra) * K + ca;
  bf16_t* lA = &As[tid * 8];
  bf16_t* lB = &Bs[tid * 8];

  floatx4 acc[4][4] = {};

  for (int k0 = 0; k0 < K; k0 += 32) {
    __syncthreads();
    async16(gA + k0, lA);
    async16(gA + k0 + (size_t)64 * K, lA + 2048);
    async16(gB + k0, lB);
    async16(gB + k0 + (size_t)64 * K, lB + 2048);
    __syncthreads();
    bf16x8 af[4], bfr[4];
#pragma unroll
    for (int i = 0; i < 4; ++i) {
      af[i]  = *(const bf16x8*)&As[(wr + i * 16 + l16) * 32 + quad * 8];
      bfr[i] = *(const bf16x8*)&Bs[(wc + i * 16 + l16) * 32 + quad * 8];
    }
#pragma unroll
    for (int mi = 0; mi < 4; ++mi)
#pragma unroll
      for (int ni = 0; ni < 4; ++ni)
        acc[mi][ni] = MFMA16(af[mi], bfr[ni], acc[mi][ni]);
  }

#pragma unroll
  for (int mi = 0; mi < 4; ++mi) {
#pragma unroll
    for (int ni = 0; ni < 4; ++ni) {
      const int row = m0 + wr + mi * 16 + quad * 4;
      const int col = n0 + wc + ni * 16 + l16;
#pragma unroll
      for (int r = 0; r < 4; ++r) {
        if (OUT_BF16)
          ((bf16_t*)Cout)[(size_t)(row + r) * N + col] = (bf16_t)acc[mi][ni][r];
        else
          ((float*)Cout)[(size_t)(row + r) * N + col] = acc[mi][ni][r];
      }
    }
  }
}

// ---------------------------------------------------------------- beta / g ([h][t] layout)
__global__ __launch_bounds__(256) void k_betag(const float* __restrict__ cba,
                                               const float* __restrict__ A_log,
                                               const float* __restrict__ dtb,
                                               float* __restrict__ beta_t,
                                               float* __restrict__ g_t) {
  int i = blockIdx.x * 256 + threadIdx.x;  // T*32
  int t = i >> 5, h = i & 31;
  float b = cba[t * 128 + h];
  float a = cba[t * 128 + 32 + h];
  beta_t[h * 4096 + t] = 1.f / (1.f + __expf(-b));
  float x = a + dtb[h];
  float sp = (x > 20.f) ? x : log1pf(__expf(x));
  g_t[h * 4096 + t] = -__expf(A_log[h]) * sp;
}

// ---------------------------------------------------------------- conv4 + silu + l2norm
__global__ __launch_bounds__(128) void k_conv(const bf16_t* __restrict__ mixed,
                                              const float* __restrict__ cw,
                                              bf16_t* __restrict__ qo,
                                              bf16_t* __restrict__ ko,
                                              bf16_t* __restrict__ vo) {
  const int t = blockIdx.y;
  const int grp = blockIdx.x;
  const int d = threadIdx.x;
  const int c = grp * 128 + d;
  const float4 wv = *(const float4*)&cw[c * 4];
  float acc = 0.f;
#pragma unroll
  for (int i = 0; i < 4; ++i) {
    int tt = t - 3 + i;
    if (tt >= 0) acc += ((const float*)&wv)[i] * (float)mixed[(size_t)tt * 8192 + c];
  }
  float val = siluf(acc);
  if (grp < 32) {
    __shared__ float red[2];
    float s = val * val;
#pragma unroll
    for (int m = 1; m < 64; m <<= 1) s += __shfl_xor(s, m);
    if ((threadIdx.x & 63) == 0) red[threadIdx.x >> 6] = s;
    __syncthreads();
    float r = rsqrtf(red[0] + red[1] + 1e-6f);
    if (grp < 16)
      qo[((size_t)t * 16 + grp) * 128 + d] = (bf16_t)(val * r * 0.08838834764831845f); // DK^-0.5 folded
    else
      ko[((size_t)t * 16 + grp - 16) * 128 + d] = (bf16_t)(val * r);
  } else {
    vo[((size_t)t * 32 + grp - 32) * 128 + d] = (bf16_t)val;
  }
}

// ---------------------------------------------------------------- k_prep
// grid = 32 heads x 64 chunks (blockIdx.x = c*32 + h). 256 threads.
// Computes per (head, chunk): decay vectors, M (decayed QK^T, bf16),
// solves (I+C)[Vt | Wsol] = [beta*V | beta*A*K] by per-column forward
// substitution (fp32), writes Vt, W' = -Wsol, K^T, smalls (A, sc).
__global__ __launch_bounds__(256, 2) void k_prep(
    const bf16_t* __restrict__ qg, const bf16_t* __restrict__ kg,
    const bf16_t* __restrict__ vg,
    const float* __restrict__ bb_t, const float* __restrict__ gb_t,
    bf16_t* __restrict__ Vt, bf16_t* __restrict__ Wlo, bf16_t* __restrict__ Whi,
    bf16_t* __restrict__ Mout, bf16_t* __restrict__ kt, float* __restrict__ smalls) {
  const int c = blockIdx.x >> 5;
  const int h = blockIdx.x & 31;
  const int kh = h >> 1;
  const int t0 = c * 64;
  const int tid = threadIdx.x, lane = tid & 63, wave = tid >> 6;
  const int quad = lane >> 4, l16 = lane & 15;

  __shared__ __align__(16) bf16_t lsKQ[2][64][136];  // [0]=K, [1]=Q (later: vals transpose)
  __shared__ float lsC[64][68];
  __shared__ float lsG[64], lsA[64], lsSc[64], lsBeta[64];

  // stage K, Q
  {
    const int r = tid >> 2, s0 = (tid & 3) * 32;
    const bf16_t* kr = kg + ((size_t)(t0 + r) * 16 + kh) * 128 + s0;
    const bf16_t* qr = qg + ((size_t)(t0 + r) * 16 + kh) * 128 + s0;
#pragma unroll
    for (int j = 0; j < 4; ++j) {
      *(uint4*)&lsKQ[0][r][s0 + j * 8] = *(const uint4*)&kr[j * 8];
      *(uint4*)&lsKQ[1][r][s0 + j * 8] = *(const uint4*)&qr[j * 8];
    }
  }
  if (wave == 0) {
    float gv = gb_t[(size_t)h * 4096 + t0 + lane];
#pragma unroll
    for (int off = 1; off < 64; off <<= 1) {
      float n = __shfl_up(gv, off);
      if (lane >= off) gv += n;
    }
    float GL = __shfl(gv, 63);
    lsG[lane] = gv;
    lsA[lane] = __expf(gv);
    lsSc[lane] = __expf(GL - gv);
    lsBeta[lane] = bb_t[(size_t)h * 4096 + t0 + lane];
  }
  __syncthreads();

  // KK, QK via MFMA; wave quadrants (wave 1 = strictly-upper -> skipped)
  const int mr = (wave >> 1) * 32, nr = (wave & 1) * 32;
  floatx4 ak[2][2] = {}, aq[2][2] = {};
  if (wave != 1) {
#pragma unroll
    for (int ks = 0; ks < 4; ++ks) {
      bf16x8 yf[2], xk[2], xq[2];
#pragma unroll
      for (int i = 0; i < 2; ++i) {
        yf[i] = *(const bf16x8*)&lsKQ[0][nr + i * 16 + l16][ks * 32 + quad * 8];
        xk[i] = *(const bf16x8*)&lsKQ[0][mr + i * 16 + l16][ks * 32 + quad * 8];
        xq[i] = *(const bf16x8*)&lsKQ[1][mr + i * 16 + l16][ks * 32 + quad * 8];
      }
#pragma unroll
      for (int i = 0; i < 2; ++i)
#pragma unroll
        for (int j = 0; j < 2; ++j) {
          ak[i][j] = MFMA16(xk[i], yf[j], ak[i][j]);
          aq[i][j] = MFMA16(xq[i], yf[j], aq[i][j]);
        }
    }
  }
  // build C (fp32 LDS) and M (bf16 global, decayed, inclusive-lower)
  bf16_t* Mb = Mout + (size_t)(h * 64 + c) * 4096;
#pragma unroll
  for (int i = 0; i < 2; ++i)
#pragma unroll
    for (int j = 0; j < 2; ++j)
#pragma unroll
      for (int r = 0; r < 4; ++r) {
        int t = mr + i * 16 + quad * 4 + r;
        int s = nr + j * 16 + l16;
        float e = __expf(lsG[t] - lsG[s]);
        float cv = (s < t) ? lsBeta[t] * e * ak[i][j][r] : 0.f;
        float mv = (s <= t) ? e * aq[i][j][r] : 0.f;
        if (wave != 1) lsC[t][s] = cv;
        Mb[t * 64 + s] = (bf16_t)mv;
      }
  __syncthreads();

  // forward substitution: thread <-> column. cols 0..127: V, 128..255: W-rhs
  const int col = tid & 127;
  const bool isW = tid >= 128;   // wave-uniform
  float vals[64];
#pragma unroll
  for (int t = 0; t < 64; ++t) {
    float b;
    if (!isW) b = (float)vg[((size_t)(t0 + t) * 32 + h) * 128 + col];
    else      b = lsA[t] * (float)lsKQ[0][t][col];
    vals[t] = lsBeta[t] * b;
  }
#pragma unroll
  for (int t = 1; t < 64; ++t) {
    float acc = vals[t];
#pragma unroll
    for (int s4 = 0; s4 <= (t - 1) >> 2; ++s4) {
      float4 cv = *(const float4*)&lsC[t][s4 * 4];   // zero-padded at/above diag
      acc -= cv.x * vals[s4 * 4 + 0];
      acc -= cv.y * vals[s4 * 4 + 1];
      acc -= cv.z * vals[s4 * 4 + 2];
      acc -= cv.w * vals[s4 * 4 + 3];
    }
    vals[t] = acc;
  }
  if (isW) {
#pragma unroll
    for (int t = 0; t < 64; ++t) vals[t] = -vals[t];  // store W' = -W
  }

  // K^T for the chain (one of the two v-heads writes it)
  if ((h & 1) == 0) {
    const int dk = tid >> 1, sh = (tid & 1) * 32;
    bf16_t* kd = kt + (size_t)(c * 16 + kh) * 8192 + (size_t)dk * 64 + sh;
#pragma unroll
    for (int j4 = 0; j4 < 4; ++j4) {
      bf16x8 v;
#pragma unroll
      for (int e = 0; e < 8; ++e) v[e] = lsKQ[0][sh + j4 * 8 + e][dk];
      *(bf16x8*)&kd[j4 * 8] = v;
    }
  }
  if (tid < 64) {
    float* sm = smalls + (size_t)(h * 64 + c) * 128;
    sm[tid] = lsA[tid];
    sm[64 + tid] = lsSc[tid];
  }
  __syncthreads();  // everyone done reading lsKQ

  // transpose vals via LDS (overlay lsKQ), pitch 272
  bf16_t* lsT = &lsKQ[0][0][0];
#pragma unroll
  for (int t = 0; t < 64; ++t) lsT[t * 272 + tid] = (bf16_t)vals[t];
  __syncthreads();

  // cooperative vectorized global writes: Vt (cols 0..127), W' (cols 128..255)
  {
    const int r = tid >> 2, part = tid & 3;
    const bf16_t* src = &lsT[r * 272 + part * 64];
    bf16_t* dst;
    if (part < 2) {
      dst = Vt + (size_t)(h * 64 + c) * 8192 + r * 128 + part * 64;
    } else {
      bf16_t* Wb = (h < 16 ? Wlo : Whi) + (size_t)((h & 15) * 64 + c) * 8192;
      dst = Wb + r * 128 + (part - 2) * 64;
    }
#pragma unroll
    for (int j = 0; j < 8; ++j)
      *(uint4*)&dst[j * 8] = *(const uint4*)&src[j * 8];
  }
}

// ---------------------------------------------------------------- k_chain
// grid = 32 heads x 2 dv-halves. 256 threads. Sequential over 64 chunks.
// Per chunk: X = Vt + W'.S ; o = A*(Q.S) + M.X ; S' = aL*S + K^T.(sc*X)
// All A-operands register-prefetched from global; only S/X live in LDS.
__global__ __launch_bounds__(256, 1) void k_chain(
    const bf16_t* __restrict__ qg, const bf16_t* __restrict__ Vt,
    const bf16_t* __restrict__ Wlo, const bf16_t* __restrict__ Whi,
    const bf16_t* __restrict__ Mg, const bf16_t* __restrict__ ktg,
    const float* __restrict__ smalls, bf16_t* __restrict__ o) {
  const int h = blockIdx.x >> 1;
  const int dv0 = (blockIdx.x & 1) * 64;
  const int kh = h >> 1;
  const int tid = threadIdx.x, lane = tid & 63, wave = tid >> 6;
  const int quad = lane >> 4, l16 = lane & 15;

  __shared__ __align__(16) bf16_t lsXT[64][72];   // X^T  [dv][t]
  __shared__ __align__(16) bf16_t lsXbT[64][72];  // (sc*X)^T
  __shared__ __align__(16) bf16_t lsS[64][136];   // S^T  [dv][dk] bf16

  const bf16_t* Wbase = (h < 16 ? Wlo : Whi) + (size_t)(h & 15) * 64 * 8192;
  const bf16_t* Vbase = Vt + (size_t)h * 64 * 8192;
  const bf16_t* Mbase = Mg + (size_t)h * 64 * 4096;
  const float*  Sbase = smalls + (size_t)h * 64 * 128;

  const int trow = wave * 16 + quad * 4;  // +r

  floatx4 sacc[2][4] = {};
  for (int i = tid; i < 64 * 136; i += 256) (&lsS[0][0])[i] = (bf16_t)0.f;

  // prefetch chunk 0 (W-frags + V-frags are one chunk ahead)
  bf16x8 nW[4];
  bf16_t nV[16];
#pragma unroll
  for (int ks = 0; ks < 4; ++ks)
    nW[ks] = *(const bf16x8*)&Wbase[(size_t)(wave * 16 + l16) * 128 + ks * 32 + quad * 8];
#pragma unroll
  for (int tn = 0; tn < 4; ++tn)
#pragma unroll
    for (int r = 0; r < 4; ++r)
      nV[tn * 4 + r] = Vbase[(size_t)(trow + r) * 128 + dv0 + tn * 16 + l16];
  __syncthreads();

  for (int cc = 0; cc < 64; ++cc) {
    const int t0 = cc * 64;
    // rotate prefetched W/V into current
    bf16x8 cWf[4];
    float cV[16];
#pragma unroll
    for (int ks = 0; ks < 4; ++ks) cWf[ks] = nW[ks];
#pragma unroll
    for (int i = 0; i < 16; ++i) cV[i] = (float)nV[i];
    if (cc + 1 < 64) {
      const bf16_t* Wn = Wbase + (size_t)(cc + 1) * 8192;
      const bf16_t* Vn = Vbase + (size_t)(cc + 1) * 8192;
#pragma unroll
      for (int ks = 0; ks < 4; ++ks)
        nW[ks] = *(const bf16x8*)&Wn[(size_t)(wave * 16 + l16) * 128 + ks * 32 + quad * 8];
#pragma unroll
      for (int tn = 0; tn < 4; ++tn)
#pragma unroll
        for (int r = 0; r < 4; ++r)
          nV[tn * 4 + r] = Vn[(size_t)(trow + r) * 128 + dv0 + tn * 16 + l16];
    }
    // same-chunk operand loads (consumed in P1, latency hidden by P0)
    bf16x8 cQf[4], cKf[4], cMf[2];
    float cA[4], cSc[4], cAL;
    {
      const bf16_t* Qc = qg + ((size_t)(t0 + wave * 16 + l16) * 16 + kh) * 128;
#pragma unroll
      for (int ks = 0; ks < 4; ++ks)
        cQf[ks] = *(const bf16x8*)&Qc[ks * 32 + quad * 8];
      const bf16_t* Kc = ktg + (size_t)(cc * 16 + kh) * 8192;
#pragma unroll
      for (int mh = 0; mh < 2; ++mh)
#pragma unroll
        for (int ks = 0; ks < 2; ++ks)
          cKf[mh * 2 + ks] =
              *(const bf16x8*)&Kc[(size_t)((wave + 4 * mh) * 16 + l16) * 64 + ks * 32 + quad * 8];
      const bf16_t* Mc = Mbase + (size_t)cc * 4096 + (wave * 16 + l16) * 64;
#pragma unroll
      for (int ks = 0; ks < 2; ++ks)
        cMf[ks] = *(const bf16x8*)&Mc[ks * 32 + quad * 8];
      const float* sm = Sbase + (size_t)cc * 128;
#pragma unroll
      for (int r = 0; r < 4; ++r) {
        cA[r] = sm[trow + r];
        cSc[r] = sm[64 + trow + r];
      }
      cAL = sm[63];
    }

    // ---- P0: X = Vt + W'.S
    floatx4 xacc[4];
#pragma unroll
    for (int tn = 0; tn < 4; ++tn)
#pragma unroll
      for (int r = 0; r < 4; ++r) xacc[tn][r] = cV[tn * 4 + r];
#pragma unroll
    for (int ks = 0; ks < 4; ++ks) {
#pragma unroll
      for (int tn = 0; tn < 4; ++tn) {
        bf16x8 bS = *(const bf16x8*)&lsS[tn * 16 + l16][ks * 32 + quad * 8];
        xacc[tn] = MFMA16(cWf[ks], bS, xacc[tn]);
      }
    }
#pragma unroll
    for (int tn = 0; tn < 4; ++tn)
#pragma unroll
      for (int r = 0; r < 4; ++r) {
        float xv = xacc[tn][r];
        lsXT[tn * 16 + l16][trow + r] = (bf16_t)xv;
        lsXbT[tn * 16 + l16][trow + r] = (bf16_t)(xv * cSc[r]);
      }
    __syncthreads();  // B1: X ready

    // ---- P1: o = A*(Q.S) + M.X ; S' = aL*S + K^T.(sc*X)
    floatx4 qacc[4] = {};
#pragma unroll
    for (int ks = 0; ks < 4; ++ks) {
#pragma unroll
      for (int tn = 0; tn < 4; ++tn) {
        bf16x8 bS = *(const bf16x8*)&lsS[tn * 16 + l16][ks * 32 + quad * 8];
        qacc[tn] = MFMA16(cQf[ks], bS, qacc[tn]);
      }
    }
#pragma unroll
    for (int tn = 0; tn < 4; ++tn)
#pragma unroll
      for (int r = 0; r < 4; ++r) qacc[tn][r] *= cA[r];
#pragma unroll
    for (int ks = 0; ks < 2; ++ks) {
#pragma unroll
      for (int tn = 0; tn < 4; ++tn) {
        bf16x8 bX = *(const bf16x8*)&lsXT[tn * 16 + l16][ks * 32 + quad * 8];
        qacc[tn] = MFMA16(cMf[ks], bX, qacc[tn]);
      }
    }
#pragma unroll
    for (int tn = 0; tn < 4; ++tn)
#pragma unroll
      for (int r = 0; r < 4; ++r)
        o[((size_t)(t0 + trow + r) * 32 + h) * 128 + dv0 + tn * 16 + l16] =
            (bf16_t)qacc[tn][r];
#pragma unroll
    for (int mh = 0; mh < 2; ++mh)
#pragma unroll
      for (int tn = 0; tn < 4; ++tn)
#pragma unroll
        for (int r = 0; r < 4; ++r) sacc[mh][tn][r] *= cAL;
#pragma unroll
    for (int ks = 0; ks < 2; ++ks) {
      bf16x8 bXb[4];
#pragma unroll
      for (int tn = 0; tn < 4; ++tn)
        bXb[tn] = *(const bf16x8*)&lsXbT[tn * 16 + l16][ks * 32 + quad * 8];
#pragma unroll
      for (int mh = 0; mh < 2; ++mh)
#pragma unroll
        for (int tn = 0; tn < 4; ++tn)
          sacc[mh][tn] = MFMA16(cKf[mh * 2 + ks], bXb[tn], sacc[mh][tn]);
    }
    __syncthreads();  // B2: lsS / XT / XbT reads done

    // ---- P2: refresh bf16 state copy (S^T layout [dv][dk])
#pragma unroll
    for (int mh = 0; mh < 2; ++mh)
#pragma unroll
      for (int tn = 0; tn < 4; ++tn)
#pragma unroll
        for (int r = 0; r < 4; ++r)
          lsS[tn * 16 + l16][(wave + 4 * mh) * 16 + quad * 4 + r] =
              (bf16_t)sacc[mh][tn][r];
    __syncthreads();  // B3
  }
}

// ---------------------------------------------------------------- RMSNorm * silu(z)
__global__ __launch_bounds__(64) void k_gate(const bf16_t* __restrict__ o,
                                             const bf16_t* __restrict__ z,
                                             const float* __restrict__ nw,
                                             bf16_t* __restrict__ y) {
  const int h = blockIdx.x, t = blockIdx.y, l = threadIdx.x;
  const bf16_t* orow = o + ((size_t)t * 32 + h) * 128;
  float o0 = (float)orow[l], o1 = (float)orow[l + 64];
  float s = o0 * o0 + o1 * o1;
#pragma unroll
  for (int m = 1; m < 64; m <<= 1) s += __shfl_xor(s, m);
  float r = rsqrtf(s * (1.f / 128.f) + 1e-6f);
  const bf16_t* zrow = z + (size_t)t * 4096 + h * 128;
  float z0 = (float)zrow[l], z1 = (float)zrow[l + 64];
  bf16_t* yrow = y + (size_t)t * 4096 + h * 128;
  yrow[l]      = (bf16_t)(o0 * r * nw[l] * siluf(z0));
  yrow[l + 64] = (bf16_t)(o1 * r * nw[l + 64] * siluf(z1));
}

// ---------------------------------------------------------------- launch
extern "C" void kernel_launch(void* const* d_in, const int* in_sizes, int n_in,
                              void* d_out, int out_size, void* d_ws, size_t ws_size,
                              hipStream_t stream) {
  const float* hidden = (const float*)d_in[0];
  const float* W_qkv  = (const float*)d_in[1];
  const float* W_z    = (const float*)d_in[2];
  const float* W_b    = (const float*)d_in[3];
  const float* W_a    = (const float*)d_in[4];
  const float* conv_w = (const float*)d_in[5];
  const float* dt_b   = (const float*)d_in[6];
  const float* A_log  = (const float*)d_in[7];
  const float* norm_w = (const float*)d_in[8];
  const float* W_out  = (const float*)d_in[9];
  float* out = (float*)d_out;

  char* w = (char*)d_ws;
  const size_t MB = 1024 * 1024;
  // region reuse (time-disjoint):
  bf16_t* hs    = (bf16_t*)(w + 0 * MB);     // 16MB; after ba-GEMM -> W_lo
  bf16_t* Wlo   = hs;
  bf16_t* wqkv  = (bf16_t*)(w + 16 * MB);    // 32MB; -> Vt (prep) -> ybuf (gate)
  bf16_t* Vtb   = wqkv;
  bf16_t* ybuf  = wqkv;
  bf16_t* wz    = (bf16_t*)(w + 48 * MB);    // 16MB; -> W_hi
  bf16_t* Whi   = wz;
  bf16_t* wout  = (bf16_t*)(w + 64 * MB);    // 16MB (live till end)
  bf16_t* wba   = (bf16_t*)(w + 80 * MB);    // 0.5MB
  bf16_t* mixed = (bf16_t*)(w + 81 * MB);    // 64MB (qkv out); after conv:
  bf16_t* obuf  = mixed;                     //   [obuf bf16 32MB @81]
  bf16_t* Mbuf  = (bf16_t*)(w + 113 * MB);   //   [M 16MB @113]
  bf16_t* ktb   = (bf16_t*)(w + 129 * MB);   //   [K^T 16MB @129]
  bf16_t* zbuf  = (bf16_t*)(w + 145 * MB);   // 32MB
  float*  cba   = (float*)(w + 177 * MB);    // 2MB; after betag -> smalls (1MB)
  float*  smalls= cba;
  bf16_t* qb    = (bf16_t*)(w + 179 * MB);   // 16MB
  bf16_t* kb    = (bf16_t*)(w + 195 * MB);   // 16MB
  bf16_t* vb    = (bf16_t*)(w + 211 * MB);   // 32MB
  float*  betab = (float*)(w + 243 * MB);    // 0.5MB [h][t]
  float*  gbuf  = (float*)(w + 243 * MB + 512 * 1024);  // 0.5MB [h][t]

  k_cvt<<<8192, 256, 0, stream>>>(hidden, hs, 2097152);
  k_cvt<<<16384, 256, 0, stream>>>(W_qkv, wqkv, 4194304);
  k_cvt<<<8192, 256, 0, stream>>>(W_z, wz, 2097152);
  k_cvt<<<8192, 256, 0, stream>>>(W_out, wout, 2097152);
  k_build_wba<<<256, 256, 0, stream>>>(W_b, W_a, wba);

  gemm_bt<true><<<dim3(64, 32), 256, 0, stream>>>(hs, wqkv, mixed, 4096, 8192, 2048);
  gemm_bt<true><<<dim3(32, 32), 256, 0, stream>>>(hs, wz, zbuf, 4096, 4096, 2048);
  gemm_bt<false><<<dim3(1, 32), 256, 0, stream>>>(hs, wba, cba, 4096, 128, 2048);
  k_betag<<<512, 256, 0, stream>>>(cba, A_log, dt_b, betab, gbuf);

  k_conv<<<dim3(64, 4096), 128, 0, stream>>>(mixed, conv_w, qb, kb, vb);

  k_prep<<<2048, 256, 0, stream>>>(qb, kb, vb, betab, gbuf,
                                   Vtb, Wlo, Whi, Mbuf, ktb, smalls);
  k_chain<<<64, 256, 0, stream>>>(qb, Vtb, Wlo, Whi, Mbuf, ktb, smalls, obuf);

  k_gate<<<dim3(32, 4096), 64, 0, stream>>>(obuf, zbuf, norm_w, ybuf);
  gemm_bt<false><<<dim3(16, 32), 256, 0, stream>>>(ybuf, wout, out, 4096, 2048, 4096);
}

// Round 4
// 982.459 us; speedup vs baseline: 1.6060x; 1.0937x over previous
//
#include <hip/hip_runtime.h>
#include <cstdint>
#include <cstddef>

typedef __bf16 bf16_t;
typedef __bf16 bf16x8 __attribute__((ext_vector_type(8)));
typedef __bf16 bf16x4 __attribute__((ext_vector_type(4)));
typedef float floatx4 __attribute__((ext_vector_type(4)));

// ---------------------------------------------------------------- helpers
__device__ __forceinline__ void async16(const bf16_t* g, bf16_t* l) {
  __builtin_amdgcn_global_load_lds(
      (const __attribute__((address_space(1))) unsigned int*)g,
      (__attribute__((address_space(3))) unsigned int*)l, 16, 0, 0);
}

// Barrier that drains ONLY lgkmcnt (LDS) — leaves prefetch global loads
// in flight across the barrier (compiler's __syncthreads drains vmcnt(0)).
__device__ __forceinline__ void barrier_lds() {
  asm volatile("s_waitcnt lgkmcnt(0)\n\ts_barrier" ::: "memory");
}

__device__ __forceinline__ float siluf(float x) { return x / (1.f + __expf(-x)); }

#define MFMA16(a, b, c) __builtin_amdgcn_mfma_f32_16x16x32_bf16(a, b, c, 0, 0, 0)

// ---------------------------------------------------------------- fp32 -> bf16
__global__ __launch_bounds__(256) void k_cvt(const float* __restrict__ in,
                                             bf16_t* __restrict__ out, int n4) {
  int i = blockIdx.x * 256 + threadIdx.x;
  if (i >= n4) return;
  const float4 f = ((const float4*)in)[i];
  bf16x4 r;
  r[0] = (bf16_t)f.x; r[1] = (bf16_t)f.y; r[2] = (bf16_t)f.z; r[3] = (bf16_t)f.w;
  ((bf16x4*)out)[i] = r;
}

// W_b rows 0..31, W_a rows 32..63, zeros 64..127
__global__ __launch_bounds__(256) void k_build_wba(const float* __restrict__ wb,
                                                   const float* __restrict__ wa,
                                                   bf16_t* __restrict__ out) {
  int i = blockIdx.x * 256 + threadIdx.x;
  int e = i * 4;
  int row = e >> 11;
  int col = e & 2047;
  float4 f = make_float4(0.f, 0.f, 0.f, 0.f);
  if (row < 32)      f = *(const float4*)&wb[row * 2048 + col];
  else if (row < 64) f = *(const float4*)&wa[(row - 32) * 2048 + col];
  bf16x4 r;
  r[0] = (bf16_t)f.x; r[1] = (bf16_t)f.y; r[2] = (bf16_t)f.z; r[3] = (bf16_t)f.w;
  *(bf16x4*)&out[e] = r;
}

// ---------------------------------------------------------------- GEMM (m97-style)
template<bool OUT_BF16>
__global__ __launch_bounds__(256) void gemm_bt(const bf16_t* __restrict__ A,
                                               const bf16_t* __restrict__ B,
                                               void* __restrict__ Cout,
                                               int M, int N, int K) {
  __shared__ __align__(16) bf16_t As[4096];
  __shared__ __align__(16) bf16_t Bs[4096];
  const int tid  = threadIdx.x;
  const int lane = tid & 63;
  const int wave = tid >> 6;
  const int quad = lane >> 4;
  const int l16  = lane & 15;
  const int wr   = (wave >> 1) * 64;
  const int wc   = (wave & 1) * 64;
  const int m0   = blockIdx.y * 128;
  const int n0   = blockIdx.x * 128;
  const int ra   = tid >> 2;
  const int ca   = (tid & 3) * 8;

  const bf16_t* gA = A + (size_t)(m0 + ra) * K + ca;
  const bf16_t* gB = B + (size_t)(n0 + ra) * K + ca;
  bf16_t* lA = &As[tid * 8];
  bf16_t* lB = &Bs[tid * 8];

  floatx4 acc[4][4] = {};

  for (int k0 = 0; k0 < K; k0 += 32) {
    __syncthreads();
    async16(gA + k0, lA);
    async16(gA + k0 + (size_t)64 * K, lA + 2048);
    async16(gB + k0, lB);
    async16(gB + k0 + (size_t)64 * K, lB + 2048);
    __syncthreads();
    bf16x8 af[4], bfr[4];
#pragma unroll
    for (int i = 0; i < 4; ++i) {
      af[i]  = *(const bf16x8*)&As[(wr + i * 16 + l16) * 32 + quad * 8];
      bfr[i] = *(const bf16x8*)&Bs[(wc + i * 16 + l16) * 32 + quad * 8];
    }
#pragma unroll
    for (int mi = 0; mi < 4; ++mi)
#pragma unroll
      for (int ni = 0; ni < 4; ++ni)
        acc[mi][ni] = MFMA16(af[mi], bfr[ni], acc[mi][ni]);
  }

#pragma unroll
  for (int mi = 0; mi < 4; ++mi) {
#pragma unroll
    for (int ni = 0; ni < 4; ++ni) {
      const int row = m0 + wr + mi * 16 + quad * 4;
      const int col = n0 + wc + ni * 16 + l16;
#pragma unroll
      for (int r = 0; r < 4; ++r) {
        if (OUT_BF16)
          ((bf16_t*)Cout)[(size_t)(row + r) * N + col] = (bf16_t)acc[mi][ni][r];
        else
          ((float*)Cout)[(size_t)(row + r) * N + col] = acc[mi][ni][r];
      }
    }
  }
}

// ---------------------------------------------------------------- beta / g ([h][t] layout)
__global__ __launch_bounds__(256) void k_betag(const float* __restrict__ cba,
                                               const float* __restrict__ A_log,
                                               const float* __restrict__ dtb,
                                               float* __restrict__ beta_t,
                                               float* __restrict__ g_t) {
  int i = blockIdx.x * 256 + threadIdx.x;  // T*32
  int t = i >> 5, h = i & 31;
  float b = cba[t * 128 + h];
  float a = cba[t * 128 + 32 + h];
  beta_t[h * 4096 + t] = 1.f / (1.f + __expf(-b));
  float x = a + dtb[h];
  float sp = (x > 20.f) ? x : log1pf(__expf(x));
  g_t[h * 4096 + t] = -__expf(A_log[h]) * sp;
}

// ---------------------------------------------------------------- conv4 + silu + l2norm
// 1-wave blocks, 8 tokens per block via sliding window. grid (64 groups, 512).
__global__ __launch_bounds__(64) void k_conv(const bf16_t* __restrict__ mixed,
                                             const float* __restrict__ cw,
                                             bf16_t* __restrict__ qo,
                                             bf16_t* __restrict__ ko,
                                             bf16_t* __restrict__ vo) {
  const int grp = blockIdx.x;
  const int t0 = blockIdx.y * 8;
  const int l = threadIdx.x;
  const int c0 = grp * 128 + l;
  const int c1 = c0 + 64;
  const float4 w0 = *(const float4*)&cw[c0 * 4];
  const float4 w1 = *(const float4*)&cw[c1 * 4];
  float h0[3], h1[3];
#pragma unroll
  for (int j = 0; j < 3; ++j) {
    int tt = t0 - 3 + j;
    h0[j] = (tt >= 0) ? (float)mixed[(size_t)tt * 8192 + c0] : 0.f;
    h1[j] = (tt >= 0) ? (float)mixed[(size_t)tt * 8192 + c1] : 0.f;
  }
#pragma unroll
  for (int i = 0; i < 8; ++i) {
    const int t = t0 + i;
    float x0 = (float)mixed[(size_t)t * 8192 + c0];
    float x1 = (float)mixed[(size_t)t * 8192 + c1];
    float a0 = w0.x * h0[0] + w0.y * h0[1] + w0.z * h0[2] + w0.w * x0;
    float a1 = w1.x * h1[0] + w1.y * h1[1] + w1.z * h1[2] + w1.w * x1;
    h0[0] = h0[1]; h0[1] = h0[2]; h0[2] = x0;
    h1[0] = h1[1]; h1[1] = h1[2]; h1[2] = x1;
    float v0 = siluf(a0), v1 = siluf(a1);
    if (grp < 32) {
      float s = v0 * v0 + v1 * v1;
#pragma unroll
      for (int m = 1; m < 64; m <<= 1) s += __shfl_xor(s, m);
      float r = rsqrtf(s + 1e-6f);
      if (grp < 16) {
        bf16_t* q = qo + ((size_t)t * 16 + grp) * 128;
        q[l]      = (bf16_t)(v0 * r * 0.08838834764831845f);  // DK^-0.5 folded
        q[l + 64] = (bf16_t)(v1 * r * 0.08838834764831845f);
      } else {
        bf16_t* k = ko + ((size_t)t * 16 + grp - 16) * 128;
        k[l]      = (bf16_t)(v0 * r);
        k[l + 64] = (bf16_t)(v1 * r);
      }
    } else {
      bf16_t* v = vo + ((size_t)t * 32 + grp - 32) * 128;
      v[l]      = (bf16_t)v0;
      v[l + 64] = (bf16_t)v1;
    }
  }
}

// ---------------------------------------------------------------- k_prep
// grid = 32 heads x 64 chunks (blockIdx.x = c*32 + h). 256 threads.
// Solves (I+C)[Vt | W] = [beta*V | beta*A*K]; writes VtT ([dv][t] transposed!),
// W' = -W ([t][dk]), M, K^T, smalls.
__global__ __launch_bounds__(256, 2) void k_prep(
    const bf16_t* __restrict__ qg, const bf16_t* __restrict__ kg,
    const bf16_t* __restrict__ vg,
    const float* __restrict__ bb_t, const float* __restrict__ gb_t,
    bf16_t* __restrict__ Vt, bf16_t* __restrict__ Wlo, bf16_t* __restrict__ Whi,
    bf16_t* __restrict__ Mout, bf16_t* __restrict__ kt, float* __restrict__ smalls) {
  const int c = blockIdx.x >> 5;
  const int h = blockIdx.x & 31;
  const int kh = h >> 1;
  const int t0 = c * 64;
  const int tid = threadIdx.x, lane = tid & 63, wave = tid >> 6;
  const int quad = lane >> 4, l16 = lane & 15;

  __shared__ __align__(16) bf16_t lsKQ[2][64][136];
  __shared__ float lsC[64][68];
  __shared__ float lsG[64], lsA[64], lsSc[64], lsBeta[64];

  {
    const int r = tid >> 2, s0 = (tid & 3) * 32;
    const bf16_t* kr = kg + ((size_t)(t0 + r) * 16 + kh) * 128 + s0;
    const bf16_t* qr = qg + ((size_t)(t0 + r) * 16 + kh) * 128 + s0;
#pragma unroll
    for (int j = 0; j < 4; ++j) {
      *(uint4*)&lsKQ[0][r][s0 + j * 8] = *(const uint4*)&kr[j * 8];
      *(uint4*)&lsKQ[1][r][s0 + j * 8] = *(const uint4*)&qr[j * 8];
    }
  }
  if (wave == 0) {
    float gv = gb_t[(size_t)h * 4096 + t0 + lane];
#pragma unroll
    for (int off = 1; off < 64; off <<= 1) {
      float n = __shfl_up(gv, off);
      if (lane >= off) gv += n;
    }
    float GL = __shfl(gv, 63);
    lsG[lane] = gv;
    lsA[lane] = __expf(gv);
    lsSc[lane] = __expf(GL - gv);
    lsBeta[lane] = bb_t[(size_t)h * 4096 + t0 + lane];
  }
  __syncthreads();

  const int mr = (wave >> 1) * 32, nr = (wave & 1) * 32;
  floatx4 ak[2][2] = {}, aq[2][2] = {};
  if (wave != 1) {
#pragma unroll
    for (int ks = 0; ks < 4; ++ks) {
      bf16x8 yf[2], xk[2], xq[2];
#pragma unroll
      for (int i = 0; i < 2; ++i) {
        yf[i] = *(const bf16x8*)&lsKQ[0][nr + i * 16 + l16][ks * 32 + quad * 8];
        xk[i] = *(const bf16x8*)&lsKQ[0][mr + i * 16 + l16][ks * 32 + quad * 8];
        xq[i] = *(const bf16x8*)&lsKQ[1][mr + i * 16 + l16][ks * 32 + quad * 8];
      }
#pragma unroll
      for (int i = 0; i < 2; ++i)
#pragma unroll
        for (int j = 0; j < 2; ++j) {
          ak[i][j] = MFMA16(xk[i], yf[j], ak[i][j]);
          aq[i][j] = MFMA16(xq[i], yf[j], aq[i][j]);
        }
    }
  }
  bf16_t* Mb = Mout + (size_t)(h * 64 + c) * 4096;
#pragma unroll
  for (int i = 0; i < 2; ++i)
#pragma unroll
    for (int j = 0; j < 2; ++j)
#pragma unroll
      for (int r = 0; r < 4; ++r) {
        int t = mr + i * 16 + quad * 4 + r;
        int s = nr + j * 16 + l16;
        float e = __expf(lsG[t] - lsG[s]);
        float cv = (s < t) ? lsBeta[t] * e * ak[i][j][r] : 0.f;
        float mv = (s <= t) ? e * aq[i][j][r] : 0.f;
        if (wave != 1) lsC[t][s] = cv;
        Mb[t * 64 + s] = (bf16_t)mv;
      }
  __syncthreads();

  // forward substitution: thread <-> column. cols 0..127: V, 128..255: W-rhs
  const int col = tid & 127;
  const bool isW = tid >= 128;
  float vals[64];
#pragma unroll
  for (int t = 0; t < 64; ++t) {
    float b;
    if (!isW) b = (float)vg[((size_t)(t0 + t) * 32 + h) * 128 + col];
    else      b = lsA[t] * (float)lsKQ[0][t][col];
    vals[t] = lsBeta[t] * b;
  }
#pragma unroll
  for (int t = 1; t < 64; ++t) {
    float acc = vals[t];
#pragma unroll
    for (int s4 = 0; s4 <= (t - 1) >> 2; ++s4) {
      float4 cv = *(const float4*)&lsC[t][s4 * 4];
      acc -= cv.x * vals[s4 * 4 + 0];
      acc -= cv.y * vals[s4 * 4 + 1];
      acc -= cv.z * vals[s4 * 4 + 2];
      acc -= cv.w * vals[s4 * 4 + 3];
    }
    vals[t] = acc;
  }

  // V columns: direct transposed write (VtT[dv][t], contiguous in t)
  if (!isW) {
    bf16_t* vd = Vt + (size_t)(h * 64 + c) * 8192 + (size_t)col * 64;
#pragma unroll
    for (int j = 0; j < 16; ++j) {
      bf16x4 p;
      p[0] = (bf16_t)vals[j * 4 + 0];
      p[1] = (bf16_t)vals[j * 4 + 1];
      p[2] = (bf16_t)vals[j * 4 + 2];
      p[3] = (bf16_t)vals[j * 4 + 3];
      *(bf16x4*)&vd[j * 4] = p;
    }
  } else {
#pragma unroll
    for (int t = 0; t < 64; ++t) vals[t] = -vals[t];  // W' = -W
  }

  // K^T for the chain
  if ((h & 1) == 0) {
    const int dk = tid >> 1, sh = (tid & 1) * 32;
    bf16_t* kd = kt + (size_t)(c * 16 + kh) * 8192 + (size_t)dk * 64 + sh;
#pragma unroll
    for (int j4 = 0; j4 < 4; ++j4) {
      bf16x8 v;
#pragma unroll
      for (int e = 0; e < 8; ++e) v[e] = lsKQ[0][sh + j4 * 8 + e][dk];
      *(bf16x8*)&kd[j4 * 8] = v;
    }
  }
  if (tid < 64) {
    float* sm = smalls + (size_t)(h * 64 + c) * 128;
    sm[tid] = lsA[tid];
    sm[64 + tid] = lsSc[tid];
  }
  __syncthreads();

  // transpose W half via LDS (overlay lsKQ), pitch 272
  bf16_t* lsT = &lsKQ[0][0][0];
  if (isW) {
#pragma unroll
    for (int t = 0; t < 64; ++t) lsT[t * 272 + tid] = (bf16_t)vals[t];
  }
  __syncthreads();

  // cooperative vectorized W' write: [t][dk 128]
  {
    const int r = tid >> 2, part = tid & 3;
    const bf16_t* src = &lsT[r * 272 + 128 + part * 32];
    bf16_t* Wb = (h < 16 ? Wlo : Whi) + (size_t)((h & 15) * 64 + c) * 8192 + r * 128 + part * 32;
#pragma unroll
    for (int j = 0; j < 4; ++j)
      *(uint4*)&Wb[j * 8] = *(const uint4*)&src[j * 8];
  }
}

// ---------------------------------------------------------------- chain prefetch
__device__ __forceinline__ void chain_prefetch(
    int c2, int wave, int l16, int quad, int trow, int dv0, int kh,
    const bf16_t* __restrict__ Wbase, const bf16_t* __restrict__ Vbase,
    const bf16_t* __restrict__ Mbase, const bf16_t* __restrict__ qg,
    const bf16_t* __restrict__ ktg, const float* __restrict__ Sbase,
    bf16x8 nW[4], bf16x8 nQ[4], bf16x8 nK[4], bf16x8 nM[2],
    bf16x4 nV[4], float4& nA, float4& nSc, float& nAL) {
  const bf16_t* Wn = Wbase + (size_t)c2 * 8192;
  const bf16_t* Vn = Vbase + (size_t)c2 * 8192;
  const bf16_t* Qn = qg + ((size_t)(c2 * 64 + wave * 16 + l16) * 16 + kh) * 128;
  const bf16_t* Kn = ktg + (size_t)(c2 * 16 + kh) * 8192;
  const bf16_t* Mn = Mbase + (size_t)c2 * 4096 + (wave * 16 + l16) * 64;
  const float* sm = Sbase + (size_t)c2 * 128;
#pragma unroll
  for (int ks = 0; ks < 4; ++ks) {
    nW[ks] = *(const bf16x8*)&Wn[(size_t)(wave * 16 + l16) * 128 + ks * 32 + quad * 8];
    nQ[ks] = *(const bf16x8*)&Qn[ks * 32 + quad * 8];
    nK[ks] = *(const bf16x8*)&Kn[(size_t)((wave + 4 * (ks >> 1)) * 16 + l16) * 64 + (ks & 1) * 32 + quad * 8];
  }
#pragma unroll
  for (int ks = 0; ks < 2; ++ks) nM[ks] = *(const bf16x8*)&Mn[ks * 32 + quad * 8];
#pragma unroll
  for (int tn = 0; tn < 4; ++tn)
    nV[tn] = *(const bf16x4*)&Vn[(size_t)(dv0 + tn * 16 + l16) * 64 + trow];
  nA = *(const float4*)&sm[trow];
  nSc = *(const float4*)&sm[64 + trow];
  nAL = sm[63];
}

// ---------------------------------------------------------------- k_chain
// grid = 64: blockIdx = half*32 + h (same-head halves share an XCD L2).
// Per chunk: X = Vt + W'.S ; o = A*(Q.S) + M.X ; S' = aL*S + K^T.(sc*X)
// All streams register-prefetched one chunk ahead; lgkm-only barriers keep
// prefetch loads in flight across barriers. bS kept in regs for P0+P1.
__global__ __launch_bounds__(256, 1) void k_chain(
    const bf16_t* __restrict__ qg, const bf16_t* __restrict__ VtT,
    const bf16_t* __restrict__ Wlo, const bf16_t* __restrict__ Whi,
    const bf16_t* __restrict__ Mg, const bf16_t* __restrict__ ktg,
    const float* __restrict__ smalls, bf16_t* __restrict__ o) {
  const int h = blockIdx.x & 31;
  const int dv0 = (blockIdx.x >> 5) * 64;
  const int kh = h >> 1;
  const int tid = threadIdx.x, lane = tid & 63, wave = tid >> 6;
  const int quad = lane >> 4, l16 = lane & 15;
  const int trow = wave * 16 + quad * 4;

  __shared__ __align__(16) bf16_t lsXT[64][72];
  __shared__ __align__(16) bf16_t lsXbT[64][72];
  __shared__ __align__(16) bf16_t lsS[64][136];

  const bf16_t* Wbase = (h < 16 ? Wlo : Whi) + (size_t)(h & 15) * 64 * 8192;
  const bf16_t* Vbase = VtT + (size_t)h * 64 * 8192;
  const bf16_t* Mbase = Mg + (size_t)h * 64 * 4096;
  const float*  Sbase = smalls + (size_t)h * 64 * 128;

  floatx4 sacc[2][4] = {};
  for (int i = tid; i < 64 * 136; i += 256) (&lsS[0][0])[i] = (bf16_t)0.f;

  bf16x8 nW[4], nQ[4], nK[4], nM[2];
  bf16x4 nV[4];
  float4 nA, nSc;
  float nAL;
  chain_prefetch(0, wave, l16, quad, trow, dv0, kh, Wbase, Vbase, Mbase, qg, ktg,
                 Sbase, nW, nQ, nK, nM, nV, nA, nSc, nAL);
  __syncthreads();

  for (int cc = 0; cc < 64; ++cc) {
    const int t0 = cc * 64;
    bf16x8 cW[4], cQ[4], cK[4], cM[2];
    float cV[16];
    float4 cA = nA, cSc = nSc;
    float cAL = nAL;
#pragma unroll
    for (int ks = 0; ks < 4; ++ks) { cW[ks] = nW[ks]; cQ[ks] = nQ[ks]; cK[ks] = nK[ks]; }
    cM[0] = nM[0]; cM[1] = nM[1];
#pragma unroll
    for (int tn = 0; tn < 4; ++tn)
#pragma unroll
      for (int r = 0; r < 4; ++r) cV[tn * 4 + r] = (float)nV[tn][r];

    if (cc + 1 < 64)
      chain_prefetch(cc + 1, wave, l16, quad, trow, dv0, kh, Wbase, Vbase, Mbase,
                     qg, ktg, Sbase, nW, nQ, nK, nM, nV, nA, nSc, nAL);

    // ---- P0: X = Vt + W'.S  (bS kept for P1)
    bf16x8 bS[4][4];
#pragma unroll
    for (int ks = 0; ks < 4; ++ks)
#pragma unroll
      for (int tn = 0; tn < 4; ++tn)
        bS[ks][tn] = *(const bf16x8*)&lsS[tn * 16 + l16][ks * 32 + quad * 8];
    floatx4 xacc[4];
#pragma unroll
    for (int tn = 0; tn < 4; ++tn)
#pragma unroll
      for (int r = 0; r < 4; ++r) xacc[tn][r] = cV[tn * 4 + r];
#pragma unroll
    for (int ks = 0; ks < 4; ++ks)
#pragma unroll
      for (int tn = 0; tn < 4; ++tn)
        xacc[tn] = MFMA16(cW[ks], bS[ks][tn], xacc[tn]);
#pragma unroll
    for (int tn = 0; tn < 4; ++tn) {
      bf16x4 px, pb;
#pragma unroll
      for (int r = 0; r < 4; ++r) {
        px[r] = (bf16_t)xacc[tn][r];
        pb[r] = (bf16_t)(xacc[tn][r] * ((const float*)&cSc)[r]);
      }
      *(bf16x4*)&lsXT[tn * 16 + l16][trow] = px;
      *(bf16x4*)&lsXbT[tn * 16 + l16][trow] = pb;
    }
    barrier_lds();  // B1: X ready; lsS reads done

    // ---- P1: o = A*(Q.S) + M.X ; S' = aL*S + K^T.(sc*X)
    floatx4 qacc[4] = {};
#pragma unroll
    for (int ks = 0; ks < 4; ++ks)
#pragma unroll
      for (int tn = 0; tn < 4; ++tn)
        qacc[tn] = MFMA16(cQ[ks], bS[ks][tn], qacc[tn]);
#pragma unroll
    for (int tn = 0; tn < 4; ++tn)
#pragma unroll
      for (int r = 0; r < 4; ++r) qacc[tn][r] *= ((const float*)&cA)[r];
#pragma unroll
    for (int ks = 0; ks < 2; ++ks)
#pragma unroll
      for (int tn = 0; tn < 4; ++tn) {
        bf16x8 bX = *(const bf16x8*)&lsXT[tn * 16 + l16][ks * 32 + quad * 8];
        qacc[tn] = MFMA16(cM[ks], bX, qacc[tn]);
      }
#pragma unroll
    for (int tn = 0; tn < 4; ++tn)
#pragma unroll
      for (int r = 0; r < 4; ++r)
        o[((size_t)(t0 + trow + r) * 32 + h) * 128 + dv0 + tn * 16 + l16] =
            (bf16_t)qacc[tn][r];
#pragma unroll
    for (int mh = 0; mh < 2; ++mh)
#pragma unroll
      for (int tn = 0; tn < 4; ++tn)
#pragma unroll
        for (int r = 0; r < 4; ++r) sacc[mh][tn][r] *= cAL;
#pragma unroll
    for (int ks = 0; ks < 2; ++ks) {
      bf16x8 bXb[4];
#pragma unroll
      for (int tn = 0; tn < 4; ++tn)
        bXb[tn] = *(const bf16x8*)&lsXbT[tn * 16 + l16][ks * 32 + quad * 8];
#pragma unroll
      for (int mh = 0; mh < 2; ++mh)
#pragma unroll
        for (int tn = 0; tn < 4; ++tn)
          sacc[mh][tn] = MFMA16(cK[mh * 2 + ks], bXb[tn], sacc[mh][tn]);
    }
    // ---- P2: refresh bf16 state (safe: all lsS reads happened before B1)
#pragma unroll
    for (int mh = 0; mh < 2; ++mh)
#pragma unroll
      for (int tn = 0; tn < 4; ++tn) {
        bf16x4 ps;
#pragma unroll
        for (int r = 0; r < 4; ++r) ps[r] = (bf16_t)sacc[mh][tn][r];
        *(bf16x4*)&lsS[tn * 16 + l16][(wave + 4 * mh) * 16 + quad * 4] = ps;
      }
    barrier_lds();  // B2: S visible; lsXT/lsXbT reads done before next P0 write
  }
}

// ---------------------------------------------------------------- RMSNorm * silu(z)
// block 256 = 4 waves, one (t,h) row per wave. grid 32768.
__global__ __launch_bounds__(256) void k_gate(const bf16_t* __restrict__ o,
                                              const bf16_t* __restrict__ z,
                                              const float* __restrict__ nw,
                                              bf16_t* __restrict__ y) {
  const int row = blockIdx.x * 4 + (threadIdx.x >> 6);  // t*32+h
  const int l = threadIdx.x & 63;
  const bf16_t* orow = o + (size_t)row * 128;
  float o0 = (float)orow[l], o1 = (float)orow[l + 64];
  float s = o0 * o0 + o1 * o1;
#pragma unroll
  for (int m = 1; m < 64; m <<= 1) s += __shfl_xor(s, m);
  float r = rsqrtf(s * (1.f / 128.f) + 1e-6f);
  const bf16_t* zrow = z + (size_t)row * 128;
  float z0 = (float)zrow[l], z1 = (float)zrow[l + 64];
  bf16_t* yrow = y + (size_t)row * 128;
  yrow[l]      = (bf16_t)(o0 * r * nw[l] * siluf(z0));
  yrow[l + 64] = (bf16_t)(o1 * r * nw[l + 64] * siluf(z1));
}

// ---------------------------------------------------------------- launch
extern "C" void kernel_launch(void* const* d_in, const int* in_sizes, int n_in,
                              void* d_out, int out_size, void* d_ws, size_t ws_size,
                              hipStream_t stream) {
  const float* hidden = (const float*)d_in[0];
  const float* W_qkv  = (const float*)d_in[1];
  const float* W_z    = (const float*)d_in[2];
  const float* W_b    = (const float*)d_in[3];
  const float* W_a    = (const float*)d_in[4];
  const float* conv_w = (const float*)d_in[5];
  const float* dt_b   = (const float*)d_in[6];
  const float* A_log  = (const float*)d_in[7];
  const float* norm_w = (const float*)d_in[8];
  const float* W_out  = (const float*)d_in[9];
  float* out = (float*)d_out;

  char* w = (char*)d_ws;
  const size_t MB = 1024 * 1024;
  bf16_t* hs    = (bf16_t*)(w + 0 * MB);     // 16MB; after ba-GEMM -> W_lo
  bf16_t* Wlo   = hs;
  bf16_t* wqkv  = (bf16_t*)(w + 16 * MB);    // 32MB; -> VtT (prep) -> ybuf (gate)
  bf16_t* Vtb   = wqkv;
  bf16_t* ybuf  = wqkv;
  bf16_t* wz    = (bf16_t*)(w + 48 * MB);    // 16MB; -> W_hi
  bf16_t* Whi   = wz;
  bf16_t* wout  = (bf16_t*)(w + 64 * MB);    // 16MB (live till end)
  bf16_t* wba   = (bf16_t*)(w + 80 * MB);    // 0.5MB
  bf16_t* mixed = (bf16_t*)(w + 81 * MB);    // 64MB (qkv out); after conv:
  bf16_t* obuf  = mixed;                     //   [obuf bf16 32MB @81]
  bf16_t* Mbuf  = (bf16_t*)(w + 113 * MB);   //   [M 16MB @113]
  bf16_t* ktb   = (bf16_t*)(w + 129 * MB);   //   [K^T 16MB @129]
  bf16_t* zbuf  = (bf16_t*)(w + 145 * MB);   // 32MB
  float*  cba   = (float*)(w + 177 * MB);    // 2MB; after betag -> smalls (1MB)
  float*  smalls= cba;
  bf16_t* qb    = (bf16_t*)(w + 179 * MB);   // 16MB
  bf16_t* kb    = (bf16_t*)(w + 195 * MB);   // 16MB
  bf16_t* vb    = (bf16_t*)(w + 211 * MB);   // 32MB
  float*  betab = (float*)(w + 243 * MB);    // 0.5MB [h][t]
  float*  gbuf  = (float*)(w + 243 * MB + 512 * 1024);  // 0.5MB [h][t]

  k_cvt<<<8192, 256, 0, stream>>>(hidden, hs, 2097152);
  k_cvt<<<16384, 256, 0, stream>>>(W_qkv, wqkv, 4194304);
  k_cvt<<<8192, 256, 0, stream>>>(W_z, wz, 2097152);
  k_cvt<<<8192, 256, 0, stream>>>(W_out, wout, 2097152);
  k_build_wba<<<256, 256, 0, stream>>>(W_b, W_a, wba);

  gemm_bt<true><<<dim3(64, 32), 256, 0, stream>>>(hs, wqkv, mixed, 4096, 8192, 2048);
  gemm_bt<true><<<dim3(32, 32), 256, 0, stream>>>(hs, wz, zbuf, 4096, 4096, 2048);
  gemm_bt<false><<<dim3(1, 32), 256, 0, stream>>>(hs, wba, cba, 4096, 128, 2048);
  k_betag<<<512, 256, 0, stream>>>(cba, A_log, dt_b, betab, gbuf);

  k_conv<<<dim3(64, 512), 64, 0, stream>>>(mixed, conv_w, qb, kb, vb);

  k_prep<<<2048, 256, 0, stream>>>(qb, kb, vb, betab, gbuf,
                                   Vtb, Wlo, Whi, Mbuf, ktb, smalls);
  k_chain<<<64, 256, 0, stream>>>(qb, Vtb, Wlo, Whi, Mbuf, ktb, smalls, obuf);

  k_gate<<<32768, 256, 0, stream>>>(obuf, zbuf, norm_w, ybuf);
  gemm_bt<false><<<dim3(16, 32), 256, 0, stream>>>(ybuf, wout, out, 4096, 2048, 4096);
}